// Round 11
// baseline (143.166 us; speedup 1.0000x reference)
//
#include <hip/hip_runtime.h>

#define ALPHA 0.3f
#define NT    50
#define B_    16
#define S_    160
#define RR    40
#define Q_    (RR / 4)            // 10 float4 per rel pair
#define NROW  (B_ * S_)           // 2560
#define NPAIR (B_ * S_ * S_)      // 409600
#define NSEG  (NT * NT)           // 2500
#define NREL4 (NPAIR * Q_)        // 4096000 float4 of rel
#define NCOL  (NT * RR + NT)      // 2050 compact floats per C row
#define CW    2052                // padded C row stride (floats), 8208B (16B-aligned)

typedef float v4f __attribute__((ext_vector_type(4)));

__global__ void zero_tab(float* __restrict__ tab, int n) {
    int i = blockIdx.x * blockDim.x + threadIdx.x;
    if (i < n) tab[i] = 0.0f;
}

// ---- per-batch position lists: deterministic counting sort of adds[b][:] ----
__global__ void build_lists(const int* __restrict__ adds,
                            int* __restrict__ colstart,   // [B_][64]
                            int* __restrict__ collist) {  // [B_][S_]
    __shared__ int tags[S_];
    __shared__ int cnt[NT];
    __shared__ int start[NT + 1];
    int b   = blockIdx.x;
    int tid = threadIdx.x;
    if (tid < S_) tags[tid] = adds[b * S_ + tid];
    __syncthreads();
    if (tid < NT) {
        int c = 0;
        for (int i = 0; i < S_; i++) c += (tags[i] == tid);
        cnt[tid] = c;
    }
    __syncthreads();
    if (tid == 0) {
        int s = 0;
        for (int t = 0; t < NT; t++) { start[t] = s; s += cnt[t]; }
        start[NT] = s;
    }
    __syncthreads();
    if (tid <= NT) colstart[b * 64 + tid] = start[tid];
    if (tid < NT) {
        int slot = start[tid];
        for (int i = 0; i < S_; i++)
            if (tags[i] == tid) collist[b * S_ + slot++] = i;
    }
}

// ---- stage 1: stream whole row into LDS, gather-reduce from LDS. NO atomics. ----
template <int TO_C>
__global__ __launch_bounds__(256) void stage1(const float* __restrict__ a_arc,
                                              const float4* __restrict__ a_rel4,
                                              const int* __restrict__ adds,
                                              const int* __restrict__ colstart,
                                              const int* __restrict__ collist,
                                              float* __restrict__ C,
                                              float* __restrict__ tab_arc,
                                              float* __restrict__ tab_rel) {
    __shared__ float4 a_lds[S_ * Q_];     // 1600 float4 = 25600 B (whole rel row)
    __shared__ float4 aarc_lds[S_ / 4];   // 40 float4 (whole arc row)
    __shared__ int    s_start[NT + 1];
    __shared__ int    s_list[S_];
    int row = blockIdx.x;                 // b*S_ + p1
    int b   = row / S_;
    int tid = threadIdx.x;

    for (int i = tid; i <= NT; i += 256) s_start[i] = colstart[b * 64 + i];
    for (int i = tid; i < S_; i += 256)  s_list[i]  = collist[b * S_ + i];

    const float4* arow = a_rel4 + (size_t)row * (S_ * Q_);
#pragma unroll
    for (int k = 0; k < 7; ++k) {         // 7*256 = 1792 >= 1600
        int idx = k * 256 + tid;
        if (idx < S_ * Q_) a_lds[idx] = arow[idx];
    }
    if (tid < S_ / 4)
        aarc_lds[tid] = ((const float4*)(a_arc + (size_t)row * S_))[tid];
    __syncthreads();

    int t1 = TO_C ? 0 : adds[row];

    for (int cell = tid; cell < NT * Q_; cell += 256) {
        int t2 = cell / Q_;
        int q  = cell - t2 * Q_;
        float4 acc = make_float4(0.f, 0.f, 0.f, 0.f);
        int e1 = s_start[t2 + 1];
        for (int e = s_start[t2]; e < e1; ++e) {
            float4 v = a_lds[s_list[e] * Q_ + q];
            acc.x += v.x; acc.y += v.y; acc.z += v.z; acc.w += v.w;
        }
        if (TO_C) {
            ((float4*)(C + (size_t)row * CW))[cell] = acc;
        } else {
            float* dst = tab_rel + (size_t)t1 * (NT * RR) + cell * 4;
            atomicAdd(dst + 0, acc.x); atomicAdd(dst + 1, acc.y);
            atomicAdd(dst + 2, acc.z); atomicAdd(dst + 3, acc.w);
        }
    }
    if (tid < NT) {
        const float* aarcf = (const float*)aarc_lds;
        float acc = 0.f;
        int e1 = s_start[tid + 1];
        for (int e = s_start[tid]; e < e1; ++e) acc += aarcf[s_list[e]];
        if (TO_C) C[(size_t)row * CW + NT * RR + tid] = acc;
        else      atomicAdd(tab_arc + t1 * NT + tid, acc);
    }
}

// ---- stage 2: reduce C rows grouped by t1 via per-batch lists, NO atomics ----
__global__ __launch_bounds__(256) void stage2(const float* __restrict__ C,
                                              const int* __restrict__ colstart,
                                              const int* __restrict__ collist,
                                              float* __restrict__ tab_arc,
                                              float* __restrict__ tab_rel) {
    int t1 = blockIdx.y;
    int c  = blockIdx.x * 256 + threadIdx.x;
    if (c >= NCOL) return;
    float acc = 0.f;
    for (int b = 0; b < B_; b++) {
        int s0 = colstart[b * 64 + t1], s1 = colstart[b * 64 + t1 + 1];
        for (int j = s0; j < s1; j++) {
            int row = b * S_ + collist[b * S_ + j];
            acc += C[(size_t)row * CW + c];
        }
    }
    if (c < NT * RR) tab_rel[t1 * (NT * RR) + c] = acc;
    else             tab_arc[t1 * NT + (c - NT * RR)] = acc;
}

// ---- ABLATION kernels (one diagnostic round; outputs overwritten by apply_v4) ----
// V0: grid-stride pure copy s_rel -> out_rel (probe structure, d_out destination)
// V1: row-block pure copy, no LDS
// V2: row-block copy + full staging prologue (live but unused in loop)
template <int V>
__global__ __launch_bounds__(256) void ab(const v4f* __restrict__ s_rel4,
                                          const int* __restrict__ pos,
                                          const float* __restrict__ tab_arc,
                                          const v4f* __restrict__ tab_rel4,
                                          v4f* __restrict__ out_rel4) {
    int tid = threadIdx.x;
    if (V == 0) {
        int t0 = blockIdx.x * 256 + tid;
#pragma unroll
        for (int k = 0; k < 8; ++k) {
            int i = t0 + k * (2048 * 256);
            if (i < NREL4)
                __builtin_nontemporal_store(s_rel4[i], out_rel4 + i);
        }
    } else {
        __shared__ v4f   s_tab[NT][Q_ + 1];
        __shared__ float s_tarc[NT];
        __shared__ int   s_pos[S_];
        int row = blockIdx.x;             // b*S_ + p1
        int b   = row / S_;
        int p1  = row - b * S_;
        if (V >= 2) {
            int base = pos[b * S_ + p1] * NT;
            for (int cell = tid; cell < NT * Q_; cell += 256) {
                int t2 = cell / Q_;
                int q  = cell - t2 * Q_;
                s_tab[t2][q] = tab_rel4[(base + t2) * Q_ + q];
            }
            if (tid < NT) s_tarc[tid] = tab_arc[base + tid];
            if (tid < S_) s_pos[tid] = pos[b * S_ + tid];
            __syncthreads();
            // keep staged data live without using it (rule #17: anti-DCE)
            v4f t = s_tab[tid & 31][tid & 7];
            float u = s_tarc[tid & 31] + (float)s_pos[tid & 127];
            asm volatile("" :: "v"(t.x), "v"(u));
        }
        const v4f* srow = s_rel4   + (size_t)row * (S_ * Q_);
        v4f*       orow = out_rel4 + (size_t)row * (S_ * Q_);
#pragma unroll
        for (int k = 0; k < 7; ++k) {
            int e = k * 256 + tid;
            if (e < S_ * Q_)
                __builtin_nontemporal_store(srow[e], orow + e);
        }
    }
}

// ---- apply v4 (control + real output): LDS-staged table + NT stores ----
__global__ __launch_bounds__(256) void apply_v4(const float* __restrict__ s_arc,
                                                const v4f* __restrict__ s_rel4,
                                                const int* __restrict__ pos,
                                                const float* __restrict__ tab_arc,
                                                const v4f* __restrict__ tab_rel4,
                                                float* __restrict__ out_arc,
                                                v4f* __restrict__ out_rel4) {
    __shared__ v4f   s_tab[NT][Q_ + 1];
    __shared__ float s_tarc[NT];
    __shared__ int   s_pos[S_];
    int row = blockIdx.x;                 // b*S_ + p1
    int b   = row / S_;
    int p1  = row - b * S_;
    int tid = threadIdx.x;

    int base = pos[b * S_ + p1] * NT;
    for (int cell = tid; cell < NT * Q_; cell += 256) {
        int t2 = cell / Q_;
        int q  = cell - t2 * Q_;
        s_tab[t2][q] = tab_rel4[(base + t2) * Q_ + q];
    }
    if (tid < NT) s_tarc[tid] = tab_arc[base + tid];
    if (tid < S_) s_pos[tid] = pos[b * S_ + tid];
    __syncthreads();

    const v4f* srow = s_rel4   + (size_t)row * (S_ * Q_);
    v4f*       orow = out_rel4 + (size_t)row * (S_ * Q_);
#pragma unroll
    for (int k = 0; k < 7; ++k) {
        int e = k * 256 + tid;
        if (e < S_ * Q_) {
            int p2 = e / Q_;
            int q  = e - p2 * Q_;
            v4f sv = srow[e];
            v4f tv = s_tab[s_pos[p2]][q];
            __builtin_nontemporal_store(sv + ALPHA * tv, orow + e);
        }
    }
    if (tid < S_) {
        float v = s_arc[(size_t)row * S_ + tid] + ALPHA * s_tarc[s_pos[tid]];
        __builtin_nontemporal_store(v, out_arc + (size_t)row * S_ + tid);
    }
}

extern "C" void kernel_launch(void* const* d_in, const int* in_sizes, int n_in,
                              void* d_out, int out_size, void* d_ws, size_t ws_size,
                              hipStream_t stream) {
    const float*  a_arc = (const float*)d_in[0];
    const float4* a_rel = (const float4*)d_in[1];
    const float*  s_arc = (const float*)d_in[2];
    const v4f*    s_rel = (const v4f*)d_in[3];
    const int*    adds  = (const int*)d_in[4];
    const int*    pos   = (const int*)d_in[5];

    // workspace layout
    float* tab_arc  = (float*)d_ws;                    // NSEG
    float* tab_rel  = tab_arc + NSEG;                  // NSEG*RR
    int*   colstart = (int*)(tab_rel + NSEG * RR);     // B_*64
    int*   collist  = colstart + B_ * 64;              // B_*S_
    float* C        = (float*)(collist + B_ * S_);     // NROW*CW
    C = (float*)(((uintptr_t)C + 15) & ~(uintptr_t)15);

    size_t need_lists = (size_t)(NSEG * (RR + 1)) * 4
                      + (size_t)(B_ * 64 + B_ * S_) * 4 + 16;
    size_t need_full  = need_lists + (size_t)NROW * CW * 4;

    float* out_arc = (float*)d_out;                    // NPAIR
    v4f*   out_rel = (v4f*)(out_arc + NPAIR);          // NREL4

    const int BLK = 256;

    build_lists<<<B_, 192, 0, stream>>>(adds, colstart, collist);

    if (ws_size >= need_full) {
        stage1<1><<<NROW, 256, 0, stream>>>(a_arc, a_rel, adds, colstart, collist,
                                            C, nullptr, nullptr);
        dim3 g2((NCOL + 255) / 256, NT);
        stage2<<<g2, 256, 0, stream>>>(C, colstart, collist, tab_arc, tab_rel);
    } else {
        int n_tab = NSEG * (RR + 1);
        zero_tab<<<(n_tab + BLK - 1) / BLK, BLK, 0, stream>>>(tab_arc, n_tab);
        stage1<0><<<NROW, 256, 0, stream>>>(a_arc, a_rel, adds, colstart, collist,
                                            nullptr, tab_arc, tab_rel);
    }

    // ---- ablation dispatches (diagnostic; deleted next round) ----
    ab<0><<<2048, 256, 0, stream>>>(s_rel, pos, tab_arc, (const v4f*)tab_rel, out_rel);
    ab<1><<<NROW, 256, 0, stream>>>(s_rel, pos, tab_arc, (const v4f*)tab_rel, out_rel);
    ab<2><<<NROW, 256, 0, stream>>>(s_rel, pos, tab_arc, (const v4f*)tab_rel, out_rel);

    apply_v4<<<NROW, 256, 0, stream>>>(s_arc, s_rel, pos, tab_arc,
                                       (const v4f*)tab_rel, out_arc, out_rel);
}

// Round 12
// 139.409 us; speedup vs baseline: 1.0269x; 1.0269x over previous
//
#include <hip/hip_runtime.h>

#define ALPHA 0.3f
#define NT    50
#define B_    16
#define S_    160
#define RR    40
#define Q_    (RR / 4)            // 10 float4 per rel pair
#define NROW  (B_ * S_)           // 2560
#define NPAIR (B_ * S_ * S_)      // 409600
#define NSEG  (NT * NT)           // 2500
#define NREL4 (NPAIR * Q_)        // 4096000 float4 of rel
#define NCOL  (NT * RR + NT)      // 2050 compact floats per C row
#define CW    2052                // padded C row stride (floats), 8208B (16B-aligned)

typedef float v4f __attribute__((ext_vector_type(4)));

__global__ void zero_tab(float* __restrict__ tab, int n) {
    int i = blockIdx.x * blockDim.x + threadIdx.x;
    if (i < n) tab[i] = 0.0f;
}

// ---- per-batch position lists: deterministic counting sort of adds[b][:] ----
__global__ void build_lists(const int* __restrict__ adds,
                            int* __restrict__ colstart,   // [B_][64]
                            int* __restrict__ collist) {  // [B_][S_]
    __shared__ int tags[S_];
    __shared__ int cnt[NT];
    __shared__ int start[NT + 1];
    int b   = blockIdx.x;
    int tid = threadIdx.x;
    if (tid < S_) tags[tid] = adds[b * S_ + tid];
    __syncthreads();
    if (tid < NT) {
        int c = 0;
        for (int i = 0; i < S_; i++) c += (tags[i] == tid);
        cnt[tid] = c;
    }
    __syncthreads();
    if (tid == 0) {
        int s = 0;
        for (int t = 0; t < NT; t++) { start[t] = s; s += cnt[t]; }
        start[NT] = s;
    }
    __syncthreads();
    if (tid <= NT) colstart[b * 64 + tid] = start[tid];
    if (tid < NT) {
        int slot = start[tid];
        for (int i = 0; i < S_; i++)
            if (tags[i] == tid) collist[b * S_ + slot++] = i;
    }
}

// ---- stage 1: stream whole row into LDS, gather-reduce from LDS. NO atomics. ----
template <int TO_C>
__global__ __launch_bounds__(256) void stage1(const float* __restrict__ a_arc,
                                              const float4* __restrict__ a_rel4,
                                              const int* __restrict__ adds,
                                              const int* __restrict__ colstart,
                                              const int* __restrict__ collist,
                                              float* __restrict__ C,
                                              float* __restrict__ tab_arc,
                                              float* __restrict__ tab_rel) {
    __shared__ float4 a_lds[S_ * Q_];     // 1600 float4 = 25600 B (whole rel row)
    __shared__ float4 aarc_lds[S_ / 4];   // 40 float4 (whole arc row)
    __shared__ int    s_start[NT + 1];
    __shared__ int    s_list[S_];
    int row = blockIdx.x;                 // b*S_ + p1
    int b   = row / S_;
    int tid = threadIdx.x;

    for (int i = tid; i <= NT; i += 256) s_start[i] = colstart[b * 64 + i];
    for (int i = tid; i < S_; i += 256)  s_list[i]  = collist[b * S_ + i];

    const float4* arow = a_rel4 + (size_t)row * (S_ * Q_);
#pragma unroll
    for (int k = 0; k < 7; ++k) {         // 7*256 = 1792 >= 1600
        int idx = k * 256 + tid;
        if (idx < S_ * Q_) a_lds[idx] = arow[idx];
    }
    if (tid < S_ / 4)
        aarc_lds[tid] = ((const float4*)(a_arc + (size_t)row * S_))[tid];
    __syncthreads();

    int t1 = TO_C ? 0 : adds[row];

    for (int cell = tid; cell < NT * Q_; cell += 256) {
        int t2 = cell / Q_;
        int q  = cell - t2 * Q_;
        float4 acc = make_float4(0.f, 0.f, 0.f, 0.f);
        int e1 = s_start[t2 + 1];
        for (int e = s_start[t2]; e < e1; ++e) {
            float4 v = a_lds[s_list[e] * Q_ + q];
            acc.x += v.x; acc.y += v.y; acc.z += v.z; acc.w += v.w;
        }
        if (TO_C) {
            ((float4*)(C + (size_t)row * CW))[cell] = acc;
        } else {
            float* dst = tab_rel + (size_t)t1 * (NT * RR) + cell * 4;
            atomicAdd(dst + 0, acc.x); atomicAdd(dst + 1, acc.y);
            atomicAdd(dst + 2, acc.z); atomicAdd(dst + 3, acc.w);
        }
    }
    if (tid < NT) {
        const float* aarcf = (const float*)aarc_lds;
        float acc = 0.f;
        int e1 = s_start[tid + 1];
        for (int e = s_start[tid]; e < e1; ++e) acc += aarcf[s_list[e]];
        if (TO_C) C[(size_t)row * CW + NT * RR + tid] = acc;
        else      atomicAdd(tab_arc + t1 * NT + tid, acc);
    }
}

// ---- stage 2: reduce C rows grouped by t1 via per-batch lists, NO atomics ----
__global__ __launch_bounds__(256) void stage2(const float* __restrict__ C,
                                              const int* __restrict__ colstart,
                                              const int* __restrict__ collist,
                                              float* __restrict__ tab_arc,
                                              float* __restrict__ tab_rel) {
    int t1 = blockIdx.y;
    int c  = blockIdx.x * 256 + threadIdx.x;
    if (c >= NCOL) return;
    float acc = 0.f;
    for (int b = 0; b < B_; b++) {
        int s0 = colstart[b * 64 + t1], s1 = colstart[b * 64 + t1 + 1];
        for (int j = s0; j < s1; j++) {
            int row = b * S_ + collist[b * S_ + j];
            acc += C[(size_t)row * CW + c];
        }
    }
    if (c < NT * RR) tab_rel[t1 * (NT * RR) + c] = acc;
    else             tab_arc[t1 * NT + (c - NT * RR)] = acc;
}

// ---- DIAGNOSTIC (visible above the 39µs fill wall): grid copy x3 passes ----
__global__ __launch_bounds__(256) void ab_copy3(const v4f* __restrict__ s_rel4,
                                                v4f* __restrict__ out_rel4) {
    int t0 = blockIdx.x * 256 + threadIdx.x;
    for (int pass = 0; pass < 3; ++pass) {
#pragma unroll
        for (int k = 0; k < 8; ++k) {
            int i = t0 + k * (2048 * 256);
            if (i < NREL4)
                __builtin_nontemporal_store(s_rel4[i], out_rel4 + i);
        }
        asm volatile("" ::: "memory");    // force re-load/re-store each pass
    }
}

// ---- apply v5: dependency-broken hot loop ----
// tpos prefetched into REGISTERS (7 independent ds_reads) before the loop;
// p2/q via carry-walk (no per-element division); loop body = global load +
// single-level LDS read + FMA + NT store  ==  the 20µs copy + 1 ds_read_b128.
__global__ __launch_bounds__(256) void apply_v5(const float* __restrict__ s_arc,
                                                const v4f* __restrict__ s_rel4,
                                                const int* __restrict__ pos,
                                                const float* __restrict__ tab_arc,
                                                const v4f* __restrict__ tab_rel4,
                                                float* __restrict__ out_arc,
                                                v4f* __restrict__ out_rel4) {
    __shared__ v4f   s_tab[NT][Q_ + 1];   // stride 176B: odd bank walk, low conflict
    __shared__ float s_tarc[NT];
    __shared__ int   s_pos[S_];
    int row = blockIdx.x;                 // b*S_ + p1
    int b   = row / S_;
    int p1  = row - b * S_;
    int tid = threadIdx.x;

    int base = pos[b * S_ + p1] * NT;     // wave-uniform
    for (int cell = tid; cell < NT * Q_; cell += 256) {
        int t2 = cell / Q_;
        int q  = cell - t2 * Q_;
        s_tab[t2][q] = tab_rel4[(base + t2) * Q_ + q];   // coalesced 8 KB
    }
    if (tid < NT) s_tarc[tid] = tab_arc[base + tid];
    if (tid < S_) s_pos[tid] = pos[b * S_ + tid];
    __syncthreads();

    // carry-walk p2/q for e_k = k*256 + tid   (256 = 25*Q_ + 6)
    int p2a[7], qa[7];
    {
        int p2 = tid / Q_, q = tid - (tid / Q_) * Q_;
#pragma unroll
        for (int k = 0; k < 7; ++k) {
            p2a[k] = p2; qa[k] = q;
            q  += 6;
            p2 += 25;
            if (q >= Q_) { q -= Q_; p2 += 1; }
        }
    }
    // prefetch tpos into registers: 7 INDEPENDENT LDS reads, no per-iter dep
    int tpos[7];
#pragma unroll
    for (int k = 0; k < 7; ++k)
        tpos[k] = (k * 256 + tid < S_ * Q_) ? s_pos[p2a[k]] : 0;

    const v4f* srow = s_rel4   + (size_t)row * (S_ * Q_);
    v4f*       orow = out_rel4 + (size_t)row * (S_ * Q_);
#pragma unroll
    for (int k = 0; k < 7; ++k) {
        int e = k * 256 + tid;
        if (e < S_ * Q_) {
            v4f sv = srow[e];                    // independent global load
            v4f tv = s_tab[tpos[k]][qa[k]];      // single-level LDS read
            __builtin_nontemporal_store(sv + ALPHA * tv, orow + e);
        }
    }
    if (tid < S_) {
        float v = s_arc[(size_t)row * S_ + tid] + ALPHA * s_tarc[s_pos[tid]];
        __builtin_nontemporal_store(v, out_arc + (size_t)row * S_ + tid);
    }
}

extern "C" void kernel_launch(void* const* d_in, const int* in_sizes, int n_in,
                              void* d_out, int out_size, void* d_ws, size_t ws_size,
                              hipStream_t stream) {
    const float*  a_arc = (const float*)d_in[0];
    const float4* a_rel = (const float4*)d_in[1];
    const float*  s_arc = (const float*)d_in[2];
    const v4f*    s_rel = (const v4f*)d_in[3];
    const int*    adds  = (const int*)d_in[4];
    const int*    pos   = (const int*)d_in[5];

    // workspace layout
    float* tab_arc  = (float*)d_ws;                    // NSEG
    float* tab_rel  = tab_arc + NSEG;                  // NSEG*RR
    int*   colstart = (int*)(tab_rel + NSEG * RR);     // B_*64
    int*   collist  = colstart + B_ * 64;              // B_*S_
    float* C        = (float*)(collist + B_ * S_);     // NROW*CW
    C = (float*)(((uintptr_t)C + 15) & ~(uintptr_t)15);

    size_t need_lists = (size_t)(NSEG * (RR + 1)) * 4
                      + (size_t)(B_ * 64 + B_ * S_) * 4 + 16;
    size_t need_full  = need_lists + (size_t)NROW * CW * 4;

    float* out_arc = (float*)d_out;                    // NPAIR
    v4f*   out_rel = (v4f*)(out_arc + NPAIR);          // NREL4

    const int BLK = 256;

    build_lists<<<B_, 192, 0, stream>>>(adds, colstart, collist);

    if (ws_size >= need_full) {
        stage1<1><<<NROW, 256, 0, stream>>>(a_arc, a_rel, adds, colstart, collist,
                                            C, nullptr, nullptr);
        dim3 g2((NCOL + 255) / 256, NT);
        stage2<<<g2, 256, 0, stream>>>(C, colstart, collist, tab_arc, tab_rel);
    } else {
        int n_tab = NSEG * (RR + 1);
        zero_tab<<<(n_tab + BLK - 1) / BLK, BLK, 0, stream>>>(tab_arc, n_tab);
        stage1<0><<<NROW, 256, 0, stream>>>(a_arc, a_rel, adds, colstart, collist,
                                            nullptr, tab_arc, tab_rel);
    }

    // diagnostic (deleted next round): visible copy-to-d_out measurement
    ab_copy3<<<2048, 256, 0, stream>>>(s_rel, out_rel);

    apply_v5<<<NROW, 256, 0, stream>>>(s_arc, s_rel, pos, tab_arc,
                                       (const v4f*)tab_rel, out_arc, out_rel);
}

// Round 13
// 81.486 us; speedup vs baseline: 1.7569x; 1.7108x over previous
//
#include <hip/hip_runtime.h>

#define ALPHA 0.3f
#define NT    50
#define B_    16
#define S_    160
#define RR    40
#define Q_    (RR / 4)            // 10 float4 per rel pair
#define NROW  (B_ * S_)           // 2560
#define NPAIR (B_ * S_ * S_)      // 409600
#define NSEG  (NT * NT)           // 2500
#define NREL4 (NPAIR * Q_)        // 4096000 float4 of rel
#define NCOL  (NT * RR + NT)      // 2050 compact floats per C row
#define CW    2052                // padded C row stride (floats), 8208B (16B-aligned)

typedef float v4f __attribute__((ext_vector_type(4)));

__global__ void zero_tab(float* __restrict__ tab, int n) {
    int i = blockIdx.x * blockDim.x + threadIdx.x;
    if (i < n) tab[i] = 0.0f;
}

// ---- per-batch position lists: deterministic counting sort of adds[b][:] ----
__global__ void build_lists(const int* __restrict__ adds,
                            int* __restrict__ colstart,   // [B_][64]
                            int* __restrict__ collist) {  // [B_][S_]
    __shared__ int tags[S_];
    __shared__ int cnt[NT];
    __shared__ int start[NT + 1];
    int b   = blockIdx.x;
    int tid = threadIdx.x;
    if (tid < S_) tags[tid] = adds[b * S_ + tid];
    __syncthreads();
    if (tid < NT) {
        int c = 0;
        for (int i = 0; i < S_; i++) c += (tags[i] == tid);
        cnt[tid] = c;
    }
    __syncthreads();
    if (tid == 0) {
        int s = 0;
        for (int t = 0; t < NT; t++) { start[t] = s; s += cnt[t]; }
        start[NT] = s;
    }
    __syncthreads();
    if (tid <= NT) colstart[b * 64 + tid] = start[tid];
    if (tid < NT) {
        int slot = start[tid];
        for (int i = 0; i < S_; i++)
            if (tags[i] == tid) collist[b * S_ + slot++] = i;
    }
}

// ---- stage 1 v3: gather-on-stage (row loaded into LDS PRE-SORTED by tag rank),
// reduce loop reads sequential address-independent LDS ranges -> pipelines.
// One 256-thread block per (b,p1) row. NO atomics on the TO_C path.
template <int TO_C>
__global__ __launch_bounds__(256) void stage1(const float* __restrict__ a_arc,
                                              const float4* __restrict__ a_rel4,
                                              const int* __restrict__ adds,
                                              const int* __restrict__ colstart,
                                              const int* __restrict__ collist,
                                              float* __restrict__ C,
                                              float* __restrict__ tab_arc,
                                              float* __restrict__ tab_rel) {
    __shared__ v4f   a_srt[S_ * Q_];      // 25600 B, sorted by tag rank
    __shared__ float aarc_srt[S_];        // 640 B, sorted arc row
    __shared__ int   s_start[NT + 1];
    __shared__ int   s_list[S_];
    int row = blockIdx.x;                 // b*S_ + p1
    int b   = row / S_;
    int tid = threadIdx.x;

    if (tid <= NT) s_start[tid] = colstart[b * 64 + tid];
    if (tid < S_)  s_list[tid]  = collist[b * S_ + tid];
    __syncthreads();                      // s_list needed for the gather-stage

    const v4f*   arow  = (const v4f*)(a_rel4 + (size_t)row * (S_ * Q_));
    const float* aarow = a_arc + (size_t)row * S_;

    // gather-stage: a_srt[j*Q_+q] = arow[s_list[j]*Q_+q]; one-touch global reads,
    // 160B contiguous per j, window (25.6 KB) is L1/L2-resident.
#pragma unroll
    for (int k = 0; k < 7; ++k) {         // 7*256 = 1792 >= 1600
        int idx = k * 256 + tid;
        if (idx < S_ * Q_) {
            int j = idx / Q_;
            int q = idx - j * Q_;
            a_srt[idx] = arow[s_list[j] * Q_ + q];
        }
    }
    if (tid < S_) aarc_srt[tid] = aarow[s_list[tid]];
    __syncthreads();

    int t1 = TO_C ? 0 : adds[row];

    // reduce: per cell (t2,q) sum a_srt[e*Q_+q] for e in [e0,e1) — addresses
    // independent of data, 4-batched for MLP.
    for (int cell = tid; cell < NT * Q_; cell += 256) {
        int t2 = cell / Q_;
        int q  = cell - t2 * Q_;
        int e  = s_start[t2];
        int e1 = s_start[t2 + 1];
        v4f acc = {0.f, 0.f, 0.f, 0.f};
        for (; e + 4 <= e1; e += 4) {
            v4f v0 = a_srt[(e + 0) * Q_ + q];
            v4f v1 = a_srt[(e + 1) * Q_ + q];
            v4f v2 = a_srt[(e + 2) * Q_ + q];
            v4f v3 = a_srt[(e + 3) * Q_ + q];
            acc += (v0 + v1) + (v2 + v3);
        }
        for (; e < e1; ++e) acc += a_srt[e * Q_ + q];
        if (TO_C) {
            ((v4f*)(C + (size_t)row * CW))[cell] = acc;
        } else {
            float* dst = tab_rel + (size_t)t1 * (NT * RR) + cell * 4;
            atomicAdd(dst + 0, acc.x); atomicAdd(dst + 1, acc.y);
            atomicAdd(dst + 2, acc.z); atomicAdd(dst + 3, acc.w);
        }
    }
    // arc: 50 cells, sequential scalar ranges
    if (tid < NT) {
        int e  = s_start[tid];
        int e1 = s_start[tid + 1];
        float acc = 0.f;
        for (; e + 4 <= e1; e += 4) {
            acc += ((aarc_srt[e] + aarc_srt[e + 1])
                  + (aarc_srt[e + 2] + aarc_srt[e + 3]));
        }
        for (; e < e1; ++e) acc += aarc_srt[e];
        if (TO_C) C[(size_t)row * CW + NT * RR + tid] = acc;
        else      atomicAdd(tab_arc + t1 * NT + tid, acc);
    }
}

// ---- stage 2: reduce C rows grouped by t1 via per-batch lists, NO atomics ----
__global__ __launch_bounds__(256) void stage2(const float* __restrict__ C,
                                              const int* __restrict__ colstart,
                                              const int* __restrict__ collist,
                                              float* __restrict__ tab_arc,
                                              float* __restrict__ tab_rel) {
    int t1 = blockIdx.y;
    int c  = blockIdx.x * 256 + threadIdx.x;
    if (c >= NCOL) return;
    float acc = 0.f;
    for (int b = 0; b < B_; b++) {
        int s0 = colstart[b * 64 + t1], s1 = colstart[b * 64 + t1 + 1];
        for (int j = s0; j < s1; j++) {
            int row = b * S_ + collist[b * S_ + j];
            acc += C[(size_t)row * CW + c];
        }
    }
    if (c < NT * RR) tab_rel[t1 * (NT * RR) + c] = acc;
    else             tab_arc[t1 * NT + (c - NT * RR)] = acc;
}

// ---- apply v5: dependency-broken hot loop (27 µs measured R12) ----
__global__ __launch_bounds__(256) void apply_v5(const float* __restrict__ s_arc,
                                                const v4f* __restrict__ s_rel4,
                                                const int* __restrict__ pos,
                                                const float* __restrict__ tab_arc,
                                                const v4f* __restrict__ tab_rel4,
                                                float* __restrict__ out_arc,
                                                v4f* __restrict__ out_rel4) {
    __shared__ v4f   s_tab[NT][Q_ + 1];   // stride 176B: odd bank walk, low conflict
    __shared__ float s_tarc[NT];
    __shared__ int   s_pos[S_];
    int row = blockIdx.x;                 // b*S_ + p1
    int b   = row / S_;
    int p1  = row - b * S_;
    int tid = threadIdx.x;

    int base = pos[b * S_ + p1] * NT;     // wave-uniform
    for (int cell = tid; cell < NT * Q_; cell += 256) {
        int t2 = cell / Q_;
        int q  = cell - t2 * Q_;
        s_tab[t2][q] = tab_rel4[(base + t2) * Q_ + q];   // coalesced 8 KB
    }
    if (tid < NT) s_tarc[tid] = tab_arc[base + tid];
    if (tid < S_) s_pos[tid] = pos[b * S_ + tid];
    __syncthreads();

    // carry-walk p2/q for e_k = k*256 + tid   (256 = 25*Q_ + 6)
    int p2a[7], qa[7];
    {
        int p2 = tid / Q_, q = tid - (tid / Q_) * Q_;
#pragma unroll
        for (int k = 0; k < 7; ++k) {
            p2a[k] = p2; qa[k] = q;
            q  += 6;
            p2 += 25;
            if (q >= Q_) { q -= Q_; p2 += 1; }
        }
    }
    // prefetch tpos into registers: 7 INDEPENDENT LDS reads, no per-iter dep
    int tpos[7];
#pragma unroll
    for (int k = 0; k < 7; ++k)
        tpos[k] = (k * 256 + tid < S_ * Q_) ? s_pos[p2a[k]] : 0;

    const v4f* srow = s_rel4   + (size_t)row * (S_ * Q_);
    v4f*       orow = out_rel4 + (size_t)row * (S_ * Q_);
#pragma unroll
    for (int k = 0; k < 7; ++k) {
        int e = k * 256 + tid;
        if (e < S_ * Q_) {
            v4f sv = srow[e];                    // independent global load
            v4f tv = s_tab[tpos[k]][qa[k]];      // single-level LDS read
            __builtin_nontemporal_store(sv + ALPHA * tv, orow + e);
        }
    }
    if (tid < S_) {
        float v = s_arc[(size_t)row * S_ + tid] + ALPHA * s_tarc[s_pos[tid]];
        __builtin_nontemporal_store(v, out_arc + (size_t)row * S_ + tid);
    }
}

extern "C" void kernel_launch(void* const* d_in, const int* in_sizes, int n_in,
                              void* d_out, int out_size, void* d_ws, size_t ws_size,
                              hipStream_t stream) {
    const float*  a_arc = (const float*)d_in[0];
    const float4* a_rel = (const float4*)d_in[1];
    const float*  s_arc = (const float*)d_in[2];
    const v4f*    s_rel = (const v4f*)d_in[3];
    const int*    adds  = (const int*)d_in[4];
    const int*    pos   = (const int*)d_in[5];

    // workspace layout
    float* tab_arc  = (float*)d_ws;                    // NSEG
    float* tab_rel  = tab_arc + NSEG;                  // NSEG*RR
    int*   colstart = (int*)(tab_rel + NSEG * RR);     // B_*64
    int*   collist  = colstart + B_ * 64;              // B_*S_
    float* C        = (float*)(collist + B_ * S_);     // NROW*CW
    C = (float*)(((uintptr_t)C + 15) & ~(uintptr_t)15);

    size_t need_lists = (size_t)(NSEG * (RR + 1)) * 4
                      + (size_t)(B_ * 64 + B_ * S_) * 4 + 16;
    size_t need_full  = need_lists + (size_t)NROW * CW * 4;

    float* out_arc = (float*)d_out;                    // NPAIR
    v4f*   out_rel = (v4f*)(out_arc + NPAIR);          // NREL4

    const int BLK = 256;

    build_lists<<<B_, 192, 0, stream>>>(adds, colstart, collist);

    if (ws_size >= need_full) {
        stage1<1><<<NROW, 256, 0, stream>>>(a_arc, a_rel, adds, colstart, collist,
                                            C, nullptr, nullptr);
        dim3 g2((NCOL + 255) / 256, NT);
        stage2<<<g2, 256, 0, stream>>>(C, colstart, collist, tab_arc, tab_rel);
    } else {
        int n_tab = NSEG * (RR + 1);
        zero_tab<<<(n_tab + BLK - 1) / BLK, BLK, 0, stream>>>(tab_arc, n_tab);
        stage1<0><<<NROW, 256, 0, stream>>>(a_arc, a_rel, adds, colstart, collist,
                                            nullptr, tab_arc, tab_rel);
    }

    apply_v5<<<NROW, 256, 0, stream>>>(s_arc, s_rel, pos, tab_arc,
                                       (const v4f*)tab_rel, out_arc, out_rel);
}

// Round 14
// 80.597 us; speedup vs baseline: 1.7763x; 1.0110x over previous
//
#include <hip/hip_runtime.h>

#define ALPHA 0.3f
#define NT    50
#define B_    16
#define S_    160
#define RR    40
#define Q_    (RR / 4)            // 10 float4 per rel pair
#define NROW  (B_ * S_)           // 2560
#define NPAIR (B_ * S_ * S_)      // 409600
#define NSEG  (NT * NT)           // 2500
#define NREL4 (NPAIR * Q_)        // 4096000 float4 of rel
#define NCOL  (NT * RR + NT)      // 2050 compact floats per C row
#define CW    2052                // padded C row stride (floats), 8208B (16B-aligned)

typedef float v4f __attribute__((ext_vector_type(4)));

__global__ void zero_tab(float* __restrict__ tab, int n) {
    int i = blockIdx.x * blockDim.x + threadIdx.x;
    if (i < n) tab[i] = 0.0f;
}

// ---- per-batch position lists: deterministic counting sort of adds[b][:] ----
__global__ void build_lists(const int* __restrict__ adds,
                            int* __restrict__ colstart,   // [B_][64]
                            int* __restrict__ collist) {  // [B_][S_]
    __shared__ int tags[S_];
    __shared__ int cnt[NT];
    __shared__ int start[NT + 1];
    int b   = blockIdx.x;
    int tid = threadIdx.x;
    if (tid < S_) tags[tid] = adds[b * S_ + tid];
    __syncthreads();
    if (tid < NT) {
        int c = 0;
        for (int i = 0; i < S_; i++) c += (tags[i] == tid);
        cnt[tid] = c;
    }
    __syncthreads();
    if (tid == 0) {
        int s = 0;
        for (int t = 0; t < NT; t++) { start[t] = s; s += cnt[t]; }
        start[NT] = s;
    }
    __syncthreads();
    if (tid <= NT) colstart[b * 64 + tid] = start[tid];
    if (tid < NT) {
        int slot = start[tid];
        for (int i = 0; i < S_; i++)
            if (tags[i] == tid) collist[b * S_ + slot++] = i;
    }
}

// ---- stage 1 v3: gather-on-stage (row loaded into LDS PRE-SORTED by tag rank),
// reduce loop reads sequential address-independent LDS ranges. NO atomics (TO_C).
template <int TO_C>
__global__ __launch_bounds__(256) void stage1(const float* __restrict__ a_arc,
                                              const float4* __restrict__ a_rel4,
                                              const int* __restrict__ adds,
                                              const int* __restrict__ colstart,
                                              const int* __restrict__ collist,
                                              float* __restrict__ C,
                                              float* __restrict__ tab_arc,
                                              float* __restrict__ tab_rel) {
    __shared__ v4f   a_srt[S_ * Q_];      // 25600 B, sorted by tag rank
    __shared__ float aarc_srt[S_];        // 640 B, sorted arc row
    __shared__ int   s_start[NT + 1];
    __shared__ int   s_list[S_];
    int row = blockIdx.x;                 // b*S_ + p1
    int b   = row / S_;
    int tid = threadIdx.x;

    if (tid <= NT) s_start[tid] = colstart[b * 64 + tid];
    if (tid < S_)  s_list[tid]  = collist[b * S_ + tid];
    __syncthreads();

    const v4f*   arow  = (const v4f*)(a_rel4 + (size_t)row * (S_ * Q_));
    const float* aarow = a_arc + (size_t)row * S_;

#pragma unroll
    for (int k = 0; k < 7; ++k) {         // 7*256 = 1792 >= 1600
        int idx = k * 256 + tid;
        if (idx < S_ * Q_) {
            int j = idx / Q_;
            int q = idx - j * Q_;
            a_srt[idx] = arow[s_list[j] * Q_ + q];
        }
    }
    if (tid < S_) aarc_srt[tid] = aarow[s_list[tid]];
    __syncthreads();

    int t1 = TO_C ? 0 : adds[row];

    for (int cell = tid; cell < NT * Q_; cell += 256) {
        int t2 = cell / Q_;
        int q  = cell - t2 * Q_;
        int e  = s_start[t2];
        int e1 = s_start[t2 + 1];
        v4f acc = {0.f, 0.f, 0.f, 0.f};
        for (; e + 4 <= e1; e += 4) {
            v4f v0 = a_srt[(e + 0) * Q_ + q];
            v4f v1 = a_srt[(e + 1) * Q_ + q];
            v4f v2 = a_srt[(e + 2) * Q_ + q];
            v4f v3 = a_srt[(e + 3) * Q_ + q];
            acc += (v0 + v1) + (v2 + v3);
        }
        for (; e < e1; ++e) acc += a_srt[e * Q_ + q];
        if (TO_C) {
            ((v4f*)(C + (size_t)row * CW))[cell] = acc;
        } else {
            float* dst = tab_rel + (size_t)t1 * (NT * RR) + cell * 4;
            atomicAdd(dst + 0, acc.x); atomicAdd(dst + 1, acc.y);
            atomicAdd(dst + 2, acc.z); atomicAdd(dst + 3, acc.w);
        }
    }
    if (tid < NT) {
        int e  = s_start[tid];
        int e1 = s_start[tid + 1];
        float acc = 0.f;
        for (; e + 4 <= e1; e += 4) {
            acc += ((aarc_srt[e] + aarc_srt[e + 1])
                  + (aarc_srt[e + 2] + aarc_srt[e + 3]));
        }
        for (; e < e1; ++e) acc += aarc_srt[e];
        if (TO_C) C[(size_t)row * CW + NT * RR + tid] = acc;
        else      atomicAdd(tab_arc + t1 * NT + tid, acc);
    }
}

// ---- stage 2: reduce C rows grouped by t1 via per-batch lists, NO atomics ----
__global__ __launch_bounds__(256) void stage2(const float* __restrict__ C,
                                              const int* __restrict__ colstart,
                                              const int* __restrict__ collist,
                                              float* __restrict__ tab_arc,
                                              float* __restrict__ tab_rel) {
    int t1 = blockIdx.y;
    int c  = blockIdx.x * 256 + threadIdx.x;
    if (c >= NCOL) return;
    float acc = 0.f;
    for (int b = 0; b < B_; b++) {
        int s0 = colstart[b * 64 + t1], s1 = colstart[b * 64 + t1 + 1];
        for (int j = s0; j < s1; j++) {
            int row = b * S_ + collist[b * S_ + j];
            acc += C[(size_t)row * CW + c];
        }
    }
    if (c < NT * RR) tab_rel[t1 * (NT * RR) + c] = acc;
    else             tab_arc[t1 * NT + (c - NT * RR)] = acc;
}

// ---- apply v6: ALL table values prefetched into REGISTERS in the prologue.
// Hot loop = global load -> register FMA -> NT store. No LDS, no syncthreads,
// no per-element table access — structurally identical to the 23.7µs copy.
__global__ __launch_bounds__(256) void apply_v6(const float* __restrict__ s_arc,
                                                const v4f* __restrict__ s_rel4,
                                                const int* __restrict__ pos,
                                                const float* __restrict__ tab_arc,
                                                const v4f* __restrict__ tab_rel4,
                                                float* __restrict__ out_arc,
                                                v4f* __restrict__ out_rel4) {
    int row = blockIdx.x;                 // b*S_ + p1
    int b   = row / S_;
    int p1  = row - b * S_;
    int tid = threadIdx.x;
    const int* posb = pos + b * S_;       // 640 B, L1-hot across the block
    int base = posb[p1] * NT;             // wave-uniform

    // carry-walk p2/q for e_k = k*256 + tid   (256 = 25*Q_ + 6)
    int p2a[7], qa[7];
    {
        int p2 = tid / Q_, q = tid - (tid / Q_) * Q_;
#pragma unroll
        for (int k = 0; k < 7; ++k) {
            p2a[k] = (p2 < S_) ? p2 : 0;  // clamp lanes past e=1599 (unused)
            qa[k]  = q;
            q  += 6;
            p2 += 25;
            if (q >= Q_) { q -= Q_; p2 += 1; }
        }
    }
    // prologue gathers: 7 pos ints (L1) -> 7 table float4s (L2, 400KB-resident)
    int tp[7];
#pragma unroll
    for (int k = 0; k < 7; ++k) tp[k] = posb[p2a[k]];
    v4f tv[7];
#pragma unroll
    for (int k = 0; k < 7; ++k) tv[k] = tab_rel4[(base + tp[k]) * Q_ + qa[k]];

    const v4f* srow = s_rel4   + (size_t)row * (S_ * Q_);
    v4f*       orow = out_rel4 + (size_t)row * (S_ * Q_);
#pragma unroll
    for (int k = 0; k < 7; ++k) {
        int e = k * 256 + tid;
        if (e < S_ * Q_) {
            v4f sv = srow[e];             // independent global load
            __builtin_nontemporal_store(sv + ALPHA * tv[k], orow + e);
        }
    }
    if (tid < S_) {
        float v = s_arc[(size_t)row * S_ + tid]
                + ALPHA * tab_arc[base + posb[tid]];
        __builtin_nontemporal_store(v, out_arc + (size_t)row * S_ + tid);
    }
}

extern "C" void kernel_launch(void* const* d_in, const int* in_sizes, int n_in,
                              void* d_out, int out_size, void* d_ws, size_t ws_size,
                              hipStream_t stream) {
    const float*  a_arc = (const float*)d_in[0];
    const float4* a_rel = (const float4*)d_in[1];
    const float*  s_arc = (const float*)d_in[2];
    const v4f*    s_rel = (const v4f*)d_in[3];
    const int*    adds  = (const int*)d_in[4];
    const int*    pos   = (const int*)d_in[5];

    // workspace layout
    float* tab_arc  = (float*)d_ws;                    // NSEG
    float* tab_rel  = tab_arc + NSEG;                  // NSEG*RR
    int*   colstart = (int*)(tab_rel + NSEG * RR);     // B_*64
    int*   collist  = colstart + B_ * 64;              // B_*S_
    float* C        = (float*)(collist + B_ * S_);     // NROW*CW
    C = (float*)(((uintptr_t)C + 15) & ~(uintptr_t)15);

    size_t need_lists = (size_t)(NSEG * (RR + 1)) * 4
                      + (size_t)(B_ * 64 + B_ * S_) * 4 + 16;
    size_t need_full  = need_lists + (size_t)NROW * CW * 4;

    float* out_arc = (float*)d_out;                    // NPAIR
    v4f*   out_rel = (v4f*)(out_arc + NPAIR);          // NREL4

    const int BLK = 256;

    build_lists<<<B_, 192, 0, stream>>>(adds, colstart, collist);

    if (ws_size >= need_full) {
        stage1<1><<<NROW, 256, 0, stream>>>(a_arc, a_rel, adds, colstart, collist,
                                            C, nullptr, nullptr);
        dim3 g2((NCOL + 255) / 256, NT);
        stage2<<<g2, 256, 0, stream>>>(C, colstart, collist, tab_arc, tab_rel);
    } else {
        int n_tab = NSEG * (RR + 1);
        zero_tab<<<(n_tab + BLK - 1) / BLK, BLK, 0, stream>>>(tab_arc, n_tab);
        stage1<0><<<NROW, 256, 0, stream>>>(a_arc, a_rel, adds, colstart, collist,
                                            nullptr, tab_arc, tab_rel);
    }

    apply_v6<<<NROW, 256, 0, stream>>>(s_arc, s_rel, pos, tab_arc,
                                       (const v4f*)tab_rel, out_arc, out_rel);
}